// Round 3
// baseline (912.909 us; speedup 1.0000x reference)
//
#include <hip/hip_runtime.h>
#include <math.h>

// Problem constants (fixed shapes from setup_inputs):
//   x [4,2048,4096] f32, W [4096,4096] f32, bias [4096] f32,
//   lora_A [16,4096] f32, lora_B [4096,16] f32, out [8192,4096] f32
#define MDIM 8192
#define NDIM 4096
#define KDIM 4096

typedef __attribute__((ext_vector_type(8))) _Float16 h8;
typedef __attribute__((ext_vector_type(4))) _Float16 h4;
typedef __attribute__((ext_vector_type(4))) float f32x4;

typedef const __attribute__((address_space(1))) void* gas_ptr;
typedef __attribute__((address_space(3))) void* las_ptr;

__device__ inline void load16_to_lds(const void* g, void* l) {
  // async global->LDS, 16B/lane; LDS dest = wave-uniform base + lane*16
  __builtin_amdgcn_global_load_lds((gas_ptr)g, (las_ptr)l, 16, 0, 0);
}

// ---------- 4x4 double helpers ----------
__device__ inline void mm4(const double* A, const double* B, double* C) {
#pragma unroll
  for (int p = 0; p < 4; ++p)
#pragma unroll
    for (int q = 0; q < 4; ++q) {
      double s = 0.0;
#pragma unroll
      for (int r = 0; r < 4; ++r) s += A[p * 4 + r] * B[r * 4 + q];
      C[p * 4 + q] = s;
    }
}
__device__ inline void mm4_bt(const double* A, const double* B, double* C) {
  // C = A * B^T
#pragma unroll
  for (int p = 0; p < 4; ++p)
#pragma unroll
    for (int q = 0; q < 4; ++q) {
      double s = 0.0;
#pragma unroll
      for (int r = 0; r < 4; ++r) s += A[p * 4 + r] * B[q * 4 + r];
      C[p * 4 + q] = s;
    }
}

// ---------- kernel 1: Gu/Gv reductions + factored Newton-Schulz ----------
__global__ void ns_kernel(const float* __restrict__ lora_A,
                          const float* __restrict__ lora_B,
                          float* __restrict__ E) {
  const int h = blockIdx.x;
  const int tid = threadIdx.x;
  const int lane = tid & 63;
  const int wave = tid >> 6;

  float gu[16], gv[16];
#pragma unroll
  for (int e = 0; e < 16; ++e) { gu[e] = 0.f; gv[e] = 0.f; }

  for (int o = tid; o < NDIM; o += 256) {
    const float4 bv = *(const float4*)(lora_B + (size_t)o * 16 + h * 4);
    const float bb[4] = {bv.x, bv.y, bv.z, bv.w};
#pragma unroll
    for (int p = 0; p < 4; ++p)
#pragma unroll
      for (int q = 0; q < 4; ++q) gu[p * 4 + q] += bb[p] * bb[q];
  }
  for (int i = tid; i < KDIM; i += 256) {
    float aa[4];
#pragma unroll
    for (int p = 0; p < 4; ++p) aa[p] = lora_A[(size_t)(h * 4 + p) * KDIM + i];
#pragma unroll
    for (int p = 0; p < 4; ++p)
#pragma unroll
      for (int q = 0; q < 4; ++q) gv[p * 4 + q] += aa[p] * aa[q];
  }

#pragma unroll
  for (int e = 0; e < 16; ++e) {
#pragma unroll
    for (int off = 32; off > 0; off >>= 1) {
      gu[e] += __shfl_down(gu[e], off, 64);
      gv[e] += __shfl_down(gv[e], off, 64);
    }
  }
  __shared__ float pu[4][16], pv[4][16];
  if (lane == 0) {
#pragma unroll
    for (int e = 0; e < 16; ++e) { pu[wave][e] = gu[e]; pv[wave][e] = gv[e]; }
  }
  __syncthreads();

  if (tid == 0) {
    double gud[16], gvd[16];
#pragma unroll
    for (int e = 0; e < 16; ++e) {
      gud[e] = (double)pu[0][e] + pu[1][e] + pu[2][e] + pu[3][e];
      gvd[e] = (double)pv[0][e] + pv[1][e] + pv[2][e] + pv[3][e];
    }
    double tr = 0.0;
#pragma unroll
    for (int e = 0; e < 16; ++e) tr += gud[e] * gvd[e];
    const double alpha = sqrt(tr);
    const double n0 = alpha + 1e-7;

    double C[16] = {0};
    C[0] = C[5] = C[10] = C[15] = 1.0 / n0;

    const double a = 3.4445, b = -4.775, c = 2.0315;
    for (int it = 0; it < 5; ++it) {
      double T1[16], D[16], DG[16], DGD[16], GuC[16], F[16], Cn[16];
      mm4(C, gvd, T1);
      mm4_bt(T1, C, D);
      mm4(D, gud, DG);
      mm4(DG, D, DGD);
      mm4(gud, C, GuC);
#pragma unroll
      for (int e = 0; e < 16; ++e) F[e] = b * D[e] + c * DGD[e];
      mm4(F, GuC, Cn);
#pragma unroll
      for (int e = 0; e < 16; ++e) C[e] = a * C[e] + Cn[e];
    }
#pragma unroll
    for (int e = 0; e < 16; ++e) E[h * 16 + e] = (float)(alpha * C[e]);
  }
}

// ---------- kernel 2 (fused): blocks [0,512) build Weff (16 rows x half-K each,
// lora_A chunk staged in LDS); [512,16896) cast x ----------
__global__ void prep_kernel(const float* __restrict__ x,
                            const float* __restrict__ W,
                            const float* __restrict__ lora_A,
                            const float* __restrict__ lora_B,
                            const float* __restrict__ E,
                            _Float16* __restrict__ Wh,
                            _Float16* __restrict__ Xh) {
  const int tid = threadIdx.x;
  if (blockIdx.x < 512) {
    __shared__ float cf[16][16];                   // [row r][k] combination coeffs
    __shared__ __align__(16) float Asm[16][1024];  // 64KB lora_A chunk
    const int o0 = (blockIdx.x >> 1) * 16;
    const int kh = (blockIdx.x & 1) * 2048;
    {
      const int r = tid >> 4, kk = tid & 15, h = kk >> 2, q = kk & 3;
      float s = 0.f;
#pragma unroll
      for (int p = 0; p < 4; ++p)
        s += lora_B[(size_t)(o0 + r) * 16 + h * 4 + p] * E[h * 16 + p * 4 + q];
      cf[r][kk] = s;
    }
    for (int kb = kh; kb < kh + 2048; kb += 1024) {
      __syncthreads();  // prev chunk's Asm readers done (also publishes cf, iter 0)
#pragma unroll
      for (int j = 0; j < 16; ++j) {
        const int f4 = tid + j * 256;  // 0..4095 float4s, fully coalesced
        const int k = f4 >> 8, c4 = f4 & 255;
        *(float4*)&Asm[k][c4 * 4] =
            *(const float4*)&lora_A[(size_t)k * KDIM + kb + (size_t)c4 * 4];
      }
      __syncthreads();
      float4 av[16];
#pragma unroll
      for (int k = 0; k < 16; ++k) av[k] = *(const float4*)&Asm[k][tid * 4];
#pragma unroll
      for (int r = 0; r < 16; ++r) {
        const size_t base = (size_t)(o0 + r) * KDIM + kb + tid * 4;
        float4 acc = *(const float4*)&W[base];
#pragma unroll
        for (int k = 0; k < 16; ++k) {
          const float cfv = cf[r][k];  // LDS broadcast
          acc.x += cfv * av[k].x; acc.y += cfv * av[k].y;
          acc.z += cfv * av[k].z; acc.w += cfv * av[k].w;
        }
        h4 pk;
        pk[0] = (_Float16)acc.x; pk[1] = (_Float16)acc.y;
        pk[2] = (_Float16)acc.z; pk[3] = (_Float16)acc.w;
        *(h4*)(Wh + base) = pk;
      }
    }
  } else {
    const size_t t = (size_t)(blockIdx.x - 512) * 256 + tid;
    const size_t base = t * 8;
    const float4 a = *(const float4*)(x + base);
    const float4 b = *(const float4*)(x + base + 4);
    h8 o;
    o[0] = (_Float16)a.x; o[1] = (_Float16)a.y; o[2] = (_Float16)a.z; o[3] = (_Float16)a.w;
    o[4] = (_Float16)b.x; o[5] = (_Float16)b.y; o[6] = (_Float16)b.z; o[7] = (_Float16)b.w;
    *(h8*)(Xh + base) = o;
  }
}

// ---------- kernel 3: 256x256 GEMM, register-level software pipeline ----------
// Phase body: BAR -> issue ds_reads for phase i+1 operands -> stage -> MFMA_i
// (compiler emits counted lgkmcnt, leaving i+1's reads in flight over the MFMA)
// -> counted vmcnt. One barrier per phase. LDS drain overlaps MFMA.
// Alternating zigzag so pre-read regs are never current-MFMA operands:
//   even tile: (0,0)(0,1)(1,1)(1,0)   odd tile: (0,1)(0,0)(1,0)(1,1)
// reads/phase: ph0:4 ph1:8 ph2:0 ph3:12(next tile's first two operands)
// Stage slots per tile t: ph0:A1(t+1) ph1:A0(t+2) ph2:B0(t+2) ph3:B1(t+2)
// Drains: vmcnt(8)@ph0-end (A1(t) landed), vmcnt(6)@ph2-end (A0/B0/B1(t+1) landed).
// Every stage gets >=3 phases of flight; vmcnt never 0 in steady state.
__launch_bounds__(512, 2)
__global__ void gemm_kernel(const _Float16* __restrict__ Xh,   // [M][K]
                            const _Float16* __restrict__ Wh,   // [N][K]
                            const float* __restrict__ bias,
                            float* __restrict__ out) {         // [M][N]
  __shared__ __align__(16) _Float16 sA0_0[128 * 64], sA0_1[128 * 64];
  __shared__ __align__(16) _Float16 sA1_0[128 * 64], sA1_1[128 * 64];
  __shared__ __align__(16) _Float16 sB0_0[128 * 64], sB0_1[128 * 64];
  __shared__ __align__(16) _Float16 sB1_0[128 * 64], sB1_1[128 * 64];

  const int tid = threadIdx.x;
  const int lane = tid & 63;
  const int wave = tid >> 6;
  const int wm = wave >> 2;       // 0..1
  const int wn = wave & 3;        // 0..3
  const int quad = lane >> 4;     // k-chunk selector
  const int r16 = lane & 15;      // row within 16x16 fragment
  const int sw = r16 & 7;         // read-side swizzle key

  // XCD-aware swizzle: 512 wgs, 8 XCDs, 64 contiguous wgs per XCD
  const int lin = blockIdx.x;
  const int wg = (lin & 7) * 64 + (lin >> 3);
  const int bm = wg >> 4;  // 0..31
  const int bn = wg & 15;  // 0..15

  // staging: chunk c of a 128x(64f16) half-tile: row=c>>3, stored slot s=c&7
  // holds logical chunk s^(row&7) (swizzle applied on pre-swizzled global source)
  const int row0 = tid >> 3;
  const int lc0 = (tid & 7) ^ (row0 & 7);
  const size_t off0 = (size_t)row0 * KDIM + lc0 * 8;
  const int ldsb = tid * 16;
  const _Float16* pA0 = Xh + (size_t)(bm * 256) * KDIM;
  const _Float16* pA1 = pA0 + (size_t)128 * KDIM;
  const _Float16* pB0 = Wh + (size_t)(bn * 256) * KDIM;
  const _Float16* pB1 = pB0 + (size_t)128 * KDIM;

  // compute-side LDS element offsets
  const int aRow = (wm * 64 + r16) * 64;
  const int bRow = (wn * 32 + r16) * 64;
  const int c0 = (quad ^ sw) * 8;
  const int c1 = ((quad + 4) ^ sw) * 8;

  f32x4 acc[2][2][4][2] = {};
  h8 a0[4][2], a1[4][2], b0[2][2], b1[2][2];

#define STAGE(arr, p, koff) do {                                               \
    load16_to_lds((p) + off0 + (koff), (char*)(arr) + ldsb);                   \
    load16_to_lds((p) + off0 + (size_t)64 * KDIM + (koff),                     \
                  (char*)(arr) + ldsb + 8192);                                 \
  } while (0)

#define FENCE() asm volatile("" ::: "memory")
#define BAR() do { FENCE(); __builtin_amdgcn_s_barrier(); FENCE(); } while (0)
#define VMC(n) asm volatile("s_waitcnt vmcnt(" #n ")" ::: "memory")

#define RDA(dst, Aarr) do { _Pragma("unroll")                                  \
    for (int f = 0; f < 4; ++f) {                                              \
      dst[f][0] = *(const h8*)&Aarr[aRow + f * 1024 + c0];                     \
      dst[f][1] = *(const h8*)&Aarr[aRow + f * 1024 + c1];                     \
    } } while (0)
#define RDB(dst, Barr) do { _Pragma("unroll")                                  \
    for (int g = 0; g < 2; ++g) {                                              \
      dst[g][0] = *(const h8*)&Barr[bRow + g * 1024 + c0];                     \
      dst[g][1] = *(const h8*)&Barr[bRow + g * 1024 + c1];                     \
    } } while (0)

#define MFMA16(MQ, NQ, AV, BV) do {                                            \
    __builtin_amdgcn_s_setprio(1);                                             \
    _Pragma("unroll")                                                          \
    for (int f = 0; f < 4; ++f)                                                \
      _Pragma("unroll")                                                        \
      for (int g = 0; g < 2; ++g) {                                            \
        acc[MQ][NQ][f][g] = __builtin_amdgcn_mfma_f32_16x16x32_f16(            \
            AV[f][0], BV[g][0], acc[MQ][NQ][f][g], 0, 0, 0);                   \
        acc[MQ][NQ][f][g] = __builtin_amdgcn_mfma_f32_16x16x32_f16(            \
            AV[f][1], BV[g][1], acc[MQ][NQ][f][g], 0, 0, 0);                   \
      }                                                                        \
    __builtin_amdgcn_s_setprio(0);                                             \
  } while (0)

// Phase: BAR; pre-reads (next phase's operands); stage; [pin]; MFMA; vmcnt.
#define PH(PRE, STG, MQ, NQ, AV, BV, VMW) do {                                 \
    BAR();                                                                     \
    PRE;                                                                       \
    STG;                                                                       \
    __builtin_amdgcn_sched_barrier(0);                                         \
    MFMA16(MQ, NQ, AV, BV);                                                    \
    VMW;                                                                       \
  } while (0)

#define NOP() do { } while (0)

// even tile t: quadrants (0,0)(0,1)(1,1)(1,0); buffers parity 0
#define TILE_EVEN(t) do {                                                      \
    PH(RDB(b1, sB1_0), STAGE(sA1_1, pA1, ((t) + 1) * 64), 0, 0, a0, b0, VMC(8)); \
    PH(RDA(a1, sA1_0), STAGE(sA0_0, pA0, ((t) + 2) * 64), 0, 1, a0, b1, NOP()); \
    PH(NOP(),          STAGE(sB0_0, pB0, ((t) + 2) * 64), 1, 1, a1, b1, VMC(6)); \
    PH({ RDA(a0, sA0_1); RDB(b1, sB1_1); },                                    \
                       STAGE(sB1_0, pB1, ((t) + 2) * 64), 1, 0, a1, b0, NOP()); \
  } while (0)

// odd tile t: quadrants (0,1)(0,0)(1,0)(1,1); buffers parity 1
#define TILE_ODD(t) do {                                                       \
    PH(RDB(b0, sB0_1), STAGE(sA1_0, pA1, ((t) + 1) * 64), 0, 1, a0, b1, VMC(8)); \
    PH(RDA(a1, sA1_1), STAGE(sA0_1, pA0, ((t) + 2) * 64), 0, 0, a0, b0, NOP()); \
    PH(NOP(),          STAGE(sB0_1, pB0, ((t) + 2) * 64), 1, 0, a1, b0, VMC(6)); \
    PH({ RDA(a0, sA0_0); RDB(b0, sB0_0); },                                    \
                       STAGE(sB1_1, pB1, ((t) + 2) * 64), 1, 1, a1, b1, NOP()); \
  } while (0)

// tile 62 (even): only A1(63) left to stage; tail drains vmcnt(8)/vmcnt(2)
#define TILE_62() do {                                                         \
    PH(RDB(b1, sB1_0), STAGE(sA1_1, pA1, 63 * 64), 0, 0, a0, b0, VMC(8));      \
    PH(RDA(a1, sA1_0), NOP(),                      0, 1, a0, b1, NOP());       \
    PH(NOP(),          NOP(),                      1, 1, a1, b1, VMC(2));      \
    PH({ RDA(a0, sA0_1); RDB(b1, sB1_1); }, NOP(), 1, 0, a1, b0, NOP());       \
  } while (0)

// tile 63 (odd): no stages, no next-tile pre-reads
#define TILE_63() do {                                                         \
    PH(RDB(b0, sB0_1), NOP(), 0, 1, a0, b1, VMC(0));                           \
    PH(RDA(a1, sA1_1), NOP(), 0, 0, a0, b0, NOP());                            \
    PH(NOP(),          NOP(), 1, 0, a1, b0, NOP());                           \
    PH(NOP(),          NOP(), 1, 1, a1, b1, NOP());                           \
  } while (0)

  // prologue: tile0 all four + tile1 A0,B0,B1 (7 stages = 14 loads);
  // vmcnt(8) drains A0(0),B0(0),B1(0); A1(0)..B1(1) stay in flight.
  STAGE(sA0_0, pA0, 0);
  STAGE(sB0_0, pB0, 0);
  STAGE(sB1_0, pB1, 0);
  STAGE(sA1_0, pA1, 0);
  STAGE(sA0_1, pA0, 64);
  STAGE(sB0_1, pB0, 64);
  STAGE(sB1_1, pB1, 64);
  VMC(8);
  BAR();
  RDA(a0, sA0_0);
  RDB(b0, sB0_0);

#pragma unroll 1
  for (int t2 = 0; t2 < 62; t2 += 2) {
    TILE_EVEN(t2);
    TILE_ODD(t2 + 1);
  }
  TILE_62();
  TILE_63();

  // epilogue: D row=(lane>>4)*4+reg (M side), col=lane&15 (N side)
#pragma unroll
  for (int mq = 0; mq < 2; ++mq)
#pragma unroll
    for (int f = 0; f < 4; ++f) {
      float* po = out + (size_t)(bm * 256 + mq * 128 + wm * 64 + f * 16 + quad * 4) * NDIM;
#pragma unroll
      for (int nq = 0; nq < 2; ++nq)
#pragma unroll
        for (int g = 0; g < 2; ++g) {
          const int ocol = bn * 256 + nq * 128 + wn * 32 + g * 16 + r16;
          const float bb = bias[ocol];
          const f32x4 v = acc[mq][nq][f][g];
#pragma unroll
          for (int rg = 0; rg < 4; ++rg)
            po[(size_t)rg * NDIM + ocol] = v[rg] + bb;
        }
    }
}

extern "C" void kernel_launch(void* const* d_in, const int* in_sizes, int n_in,
                              void* d_out, int out_size, void* d_ws, size_t ws_size,
                              hipStream_t stream) {
  const float* x      = (const float*)d_in[0];  // [8192,4096]
  const float* W      = (const float*)d_in[1];  // [4096,4096]
  const float* bias   = (const float*)d_in[2];  // [4096]
  const float* lora_A = (const float*)d_in[3];  // [16,4096]
  const float* lora_B = (const float*)d_in[4];  // [4096,16]
  float* out = (float*)d_out;

  char* ws = (char*)d_ws;
  float* E = (float*)ws;                                     // 64 floats
  _Float16* Wh = (_Float16*)(ws + 1024);                     // 4096*4096*2 B
  _Float16* Xh = (_Float16*)(ws + 1024 + (size_t)NDIM * KDIM * 2);  // 8192*4096*2 B

  ns_kernel<<<dim3(4), dim3(256), 0, stream>>>(lora_A, lora_B, E);
  prep_kernel<<<dim3(512 + (MDIM * KDIM) / (256 * 8)), dim3(256), 0, stream>>>(
      x, W, lora_A, lora_B, E, Wh, Xh);
  gemm_kernel<<<dim3(512), dim3(512), 0, stream>>>(Xh, Wh, bias, out);
}

// Round 4
// 583.525 us; speedup vs baseline: 1.5645x; 1.5645x over previous
//
#include <hip/hip_runtime.h>
#include <math.h>

// Problem constants (fixed shapes from setup_inputs):
//   x [4,2048,4096] f32, W [4096,4096] f32, bias [4096] f32,
//   lora_A [16,4096] f32, lora_B [4096,16] f32, out [8192,4096] f32
#define MDIM 8192
#define NDIM 4096
#define KDIM 4096

typedef __attribute__((ext_vector_type(8))) _Float16 h8;
typedef __attribute__((ext_vector_type(4))) _Float16 h4;
typedef __attribute__((ext_vector_type(4))) float f32x4;

typedef const __attribute__((address_space(1))) void* gas_ptr;
typedef __attribute__((address_space(3))) void* las_ptr;

__device__ inline void load16_to_lds(const void* g, void* l) {
  // async global->LDS, 16B/lane; LDS dest = wave-uniform base + lane*16
  __builtin_amdgcn_global_load_lds((gas_ptr)g, (las_ptr)l, 16, 0, 0);
}

// ---------- 4x4 double helpers ----------
__device__ inline void mm4(const double* A, const double* B, double* C) {
#pragma unroll
  for (int p = 0; p < 4; ++p)
#pragma unroll
    for (int q = 0; q < 4; ++q) {
      double s = 0.0;
#pragma unroll
      for (int r = 0; r < 4; ++r) s += A[p * 4 + r] * B[r * 4 + q];
      C[p * 4 + q] = s;
    }
}
__device__ inline void mm4_bt(const double* A, const double* B, double* C) {
  // C = A * B^T
#pragma unroll
  for (int p = 0; p < 4; ++p)
#pragma unroll
    for (int q = 0; q < 4; ++q) {
      double s = 0.0;
#pragma unroll
      for (int r = 0; r < 4; ++r) s += A[p * 4 + r] * B[q * 4 + r];
      C[p * 4 + q] = s;
    }
}

// ---------- kernel 1: Gu/Gv reductions + factored Newton-Schulz ----------
__global__ void ns_kernel(const float* __restrict__ lora_A,
                          const float* __restrict__ lora_B,
                          float* __restrict__ E) {
  const int h = blockIdx.x;
  const int tid = threadIdx.x;
  const int lane = tid & 63;
  const int wave = tid >> 6;

  float gu[16], gv[16];
#pragma unroll
  for (int e = 0; e < 16; ++e) { gu[e] = 0.f; gv[e] = 0.f; }

  for (int o = tid; o < NDIM; o += 256) {
    const float4 bv = *(const float4*)(lora_B + (size_t)o * 16 + h * 4);
    const float bb[4] = {bv.x, bv.y, bv.z, bv.w};
#pragma unroll
    for (int p = 0; p < 4; ++p)
#pragma unroll
      for (int q = 0; q < 4; ++q) gu[p * 4 + q] += bb[p] * bb[q];
  }
  for (int i = tid; i < KDIM; i += 256) {
    float aa[4];
#pragma unroll
    for (int p = 0; p < 4; ++p) aa[p] = lora_A[(size_t)(h * 4 + p) * KDIM + i];
#pragma unroll
    for (int p = 0; p < 4; ++p)
#pragma unroll
      for (int q = 0; q < 4; ++q) gv[p * 4 + q] += aa[p] * aa[q];
  }

#pragma unroll
  for (int e = 0; e < 16; ++e) {
#pragma unroll
    for (int off = 32; off > 0; off >>= 1) {
      gu[e] += __shfl_down(gu[e], off, 64);
      gv[e] += __shfl_down(gv[e], off, 64);
    }
  }
  __shared__ float pu[4][16], pv[4][16];
  if (lane == 0) {
#pragma unroll
    for (int e = 0; e < 16; ++e) { pu[wave][e] = gu[e]; pv[wave][e] = gv[e]; }
  }
  __syncthreads();

  if (tid == 0) {
    double gud[16], gvd[16];
#pragma unroll
    for (int e = 0; e < 16; ++e) {
      gud[e] = (double)pu[0][e] + pu[1][e] + pu[2][e] + pu[3][e];
      gvd[e] = (double)pv[0][e] + pv[1][e] + pv[2][e] + pv[3][e];
    }
    double tr = 0.0;
#pragma unroll
    for (int e = 0; e < 16; ++e) tr += gud[e] * gvd[e];
    const double alpha = sqrt(tr);
    const double n0 = alpha + 1e-7;

    double C[16] = {0};
    C[0] = C[5] = C[10] = C[15] = 1.0 / n0;

    const double a = 3.4445, b = -4.775, c = 2.0315;
    for (int it = 0; it < 5; ++it) {
      double T1[16], D[16], DG[16], DGD[16], GuC[16], F[16], Cn[16];
      mm4(C, gvd, T1);
      mm4_bt(T1, C, D);
      mm4(D, gud, DG);
      mm4(DG, D, DGD);
      mm4(gud, C, GuC);
#pragma unroll
      for (int e = 0; e < 16; ++e) F[e] = b * D[e] + c * DGD[e];
      mm4(F, GuC, Cn);
#pragma unroll
      for (int e = 0; e < 16; ++e) C[e] = a * C[e] + Cn[e];
    }
#pragma unroll
    for (int e = 0; e < 16; ++e) E[h * 16 + e] = (float)(alpha * C[e]);
  }
}

// ---------- kernel 2a: Weff = f16(W + A^T coef), 512 blocks x 16 rows x half-K ----------
__global__ void weff_kernel(const float* __restrict__ W,
                            const float* __restrict__ lora_A,
                            const float* __restrict__ lora_B,
                            const float* __restrict__ E,
                            _Float16* __restrict__ Wh) {
  const int tid = threadIdx.x;
  __shared__ float cf[16][16];                   // [row r][k] combination coeffs
  __shared__ __align__(16) float Asm[16][1024];  // 64KB lora_A chunk
  const int o0 = (blockIdx.x >> 1) * 16;
  const int kh = (blockIdx.x & 1) * 2048;
  {
    const int r = tid >> 4, kk = tid & 15, h = kk >> 2, q = kk & 3;
    float s = 0.f;
#pragma unroll
    for (int p = 0; p < 4; ++p)
      s += lora_B[(size_t)(o0 + r) * 16 + h * 4 + p] * E[h * 16 + p * 4 + q];
    cf[r][kk] = s;
  }
  for (int kb = kh; kb < kh + 2048; kb += 1024) {
    __syncthreads();  // prev chunk's Asm readers done (also publishes cf, iter 0)
#pragma unroll
    for (int j = 0; j < 16; ++j) {
      const int f4 = tid + j * 256;  // 0..4095 float4s, fully coalesced
      const int k = f4 >> 8, c4 = f4 & 255;
      *(float4*)&Asm[k][c4 * 4] =
          *(const float4*)&lora_A[(size_t)k * KDIM + kb + (size_t)c4 * 4];
    }
    __syncthreads();
    float4 av[16];
#pragma unroll
    for (int k = 0; k < 16; ++k) av[k] = *(const float4*)&Asm[k][tid * 4];
#pragma unroll
    for (int r = 0; r < 16; ++r) {
      const size_t base = (size_t)(o0 + r) * KDIM + kb + tid * 4;
      float4 acc = *(const float4*)&W[base];
#pragma unroll
      for (int k = 0; k < 16; ++k) {
        const float cfv = cf[r][k];  // LDS broadcast
        acc.x += cfv * av[k].x; acc.y += cfv * av[k].y;
        acc.z += cfv * av[k].z; acc.w += cfv * av[k].w;
      }
      h4 pk;
      pk[0] = (_Float16)acc.x; pk[1] = (_Float16)acc.y;
      pk[2] = (_Float16)acc.z; pk[3] = (_Float16)acc.w;
      *(h4*)(Wh + base) = pk;
    }
  }
}

// ---------- kernel 2b: cast x f32 -> f16 (separate kernel for rocprof visibility) ----------
__global__ void xcast_kernel(const float* __restrict__ x,
                             _Float16* __restrict__ Xh) {
  const size_t t = (size_t)blockIdx.x * 256 + threadIdx.x;
  const size_t base = t * 8;
  const float4 a = *(const float4*)(x + base);
  const float4 b = *(const float4*)(x + base + 4);
  h8 o;
  o[0] = (_Float16)a.x; o[1] = (_Float16)a.y; o[2] = (_Float16)a.z; o[3] = (_Float16)a.w;
  o[4] = (_Float16)b.x; o[5] = (_Float16)b.y; o[6] = (_Float16)b.z; o[7] = (_Float16)b.w;
  *(h8*)(Xh + base) = o;
}

// ---------- kernel 3: 256x256 GEMM, round-2 skeleton + counted-drain staging ----------
// Zigzag (0,0)->(1,0)->(1,1)->(0,1): a0 & b1 held across two phases ->
// 24 ds_read_b128/tile/wave (the floor: A 16 + B 8). No cross-phase pre-reads,
// no sched_barrier (round-3 spill lesson).
// Stage slots (2 loads each), tile t: ph0: A0(t+1), ph1: B1(t+1),
//                                     ph2: B0(t+2), ph3: A1(t+2).
// WAR audit (stage write vs last LDS read of same buffer, barrier-separated):
//   A0(t+1)@ph0 -> A0(t-1) last read t-1.ph0   | B1(t+1)@ph1 -> B1(t-1) read t-1.ph2
//   B0(t+2)@ph2 -> B0(t) last read t.ph0       | A1(t+2)@ph3 -> A1(t) last read t.ph1
// Drain: uniform vmcnt(6) at EVERY phase end (8 outstanding after issue ->
// completes the stage issued 3 phases earlier; flight ~3-4 phases >> 900cyc HBM):
//   A0(t) [staged t-1.ph0, drained t-1.ph3]  B0(t) [t-2.ph2, drained t-1.ph1]
//   A1(t) [t-2.ph3, drained t-1.ph2]         B1(t) [t-1.ph1, drained t.ph0]
// vmcnt never 0 in steady state; explicit 4/2/0 tail in tiles 62/63.
__launch_bounds__(512, 2)
__global__ void gemm_kernel(const _Float16* __restrict__ Xh,   // [M][K]
                            const _Float16* __restrict__ Wh,   // [N][K]
                            const float* __restrict__ bias,
                            float* __restrict__ out) {         // [M][N]
  __shared__ __align__(16) _Float16 sA0_0[128 * 64], sA0_1[128 * 64];
  __shared__ __align__(16) _Float16 sA1_0[128 * 64], sA1_1[128 * 64];
  __shared__ __align__(16) _Float16 sB0_0[128 * 64], sB0_1[128 * 64];
  __shared__ __align__(16) _Float16 sB1_0[128 * 64], sB1_1[128 * 64];

  const int tid = threadIdx.x;
  const int lane = tid & 63;
  const int wave = tid >> 6;
  const int wm = wave >> 2;       // 0..1
  const int wn = wave & 3;        // 0..3
  const int quad = lane >> 4;     // k-chunk selector
  const int r16 = lane & 15;      // row within 16x16 fragment
  const int sw = r16 & 7;         // read-side swizzle key

  // XCD-aware swizzle: 512 wgs, 8 XCDs, 64 contiguous wgs per XCD
  const int lin = blockIdx.x;
  const int wg = (lin & 7) * 64 + (lin >> 3);
  const int bm = wg >> 4;  // 0..31
  const int bn = wg & 15;  // 0..15

  // staging: chunk c of a 128x(64f16) half-tile: row=c>>3, stored slot s=c&7
  // holds logical chunk s^(row&7) (swizzle applied on pre-swizzled global source)
  const int row0 = tid >> 3;
  const int lc0 = (tid & 7) ^ (row0 & 7);
  const size_t off0 = (size_t)row0 * KDIM + lc0 * 8;
  const int ldsb = tid * 16;
  const _Float16* pA0 = Xh + (size_t)(bm * 256) * KDIM;
  const _Float16* pA1 = pA0 + (size_t)128 * KDIM;
  const _Float16* pB0 = Wh + (size_t)(bn * 256) * KDIM;
  const _Float16* pB1 = pB0 + (size_t)128 * KDIM;

  // compute-side LDS element offsets
  const int aRow = (wm * 64 + r16) * 64;
  const int bRow = (wn * 32 + r16) * 64;
  const int c0 = (quad ^ sw) * 8;
  const int c1 = ((quad + 4) ^ sw) * 8;

  f32x4 acc[2][2][4][2] = {};
  h8 a0[4][2], a1[4][2], b0[2][2], b1[2][2];

#define STAGE(arr, p, koff) do {                                               \
    load16_to_lds((p) + off0 + (koff), (char*)(arr) + ldsb);                   \
    load16_to_lds((p) + off0 + (size_t)64 * KDIM + (koff),                     \
                  (char*)(arr) + ldsb + 8192);                                 \
  } while (0)

#define FENCE() asm volatile("" ::: "memory")
#define BAR() do { FENCE(); __builtin_amdgcn_s_barrier(); FENCE(); } while (0)
#define VMC(n) asm volatile("s_waitcnt vmcnt(" #n ")" ::: "memory")

#define RDA(dst, Aarr) do { _Pragma("unroll")                                  \
    for (int f = 0; f < 4; ++f) {                                              \
      dst[f][0] = *(const h8*)&Aarr[aRow + f * 1024 + c0];                     \
      dst[f][1] = *(const h8*)&Aarr[aRow + f * 1024 + c1];                     \
    } } while (0)
#define RDB(dst, Barr) do { _Pragma("unroll")                                  \
    for (int g = 0; g < 2; ++g) {                                              \
      dst[g][0] = *(const h8*)&Barr[bRow + g * 1024 + c0];                     \
      dst[g][1] = *(const h8*)&Barr[bRow + g * 1024 + c1];                     \
    } } while (0)

#define MFMA16(MQ, NQ, AV, BV) do {                                            \
    __builtin_amdgcn_s_setprio(1);                                             \
    _Pragma("unroll")                                                          \
    for (int f = 0; f < 4; ++f)                                                \
      _Pragma("unroll")                                                        \
      for (int g = 0; g < 2; ++g) {                                            \
        acc[MQ][NQ][f][g] = __builtin_amdgcn_mfma_f32_16x16x32_f16(            \
            AV[f][0], BV[g][0], acc[MQ][NQ][f][g], 0, 0, 0);                   \
        acc[MQ][NQ][f][g] = __builtin_amdgcn_mfma_f32_16x16x32_f16(            \
            AV[f][1], BV[g][1], acc[MQ][NQ][f][g], 0, 0, 0);                   \
      }                                                                        \
    __builtin_amdgcn_s_setprio(0);                                             \
  } while (0)

#define NOP() do { } while (0)

// Phase: reads; stage; BAR (publishes prev drains; compiler emits counted
// lgkmcnt before MFMA's first operand use); MFMA; vmcnt; BAR.
#define PH(RDS, STG, MQ, NQ, AV, BV, VMW) do {                                 \
    RDS;                                                                       \
    STG;                                                                       \
    BAR();                                                                     \
    MFMA16(MQ, NQ, AV, BV);                                                    \
    VMW;                                                                       \
    BAR();                                                                     \
  } while (0)

// even tile t: cur = parity0 buffers, other = parity1
#define TILE_EVEN(t) do {                                                      \
    PH({ RDA(a0, sA0_0); RDB(b0, sB0_0); },                                    \
       STAGE(sA0_1, pA0, ((t) + 1) * 64), 0, 0, a0, b0, VMC(6));               \
    PH(RDA(a1, sA1_0), STAGE(sB1_1, pB1, ((t) + 1) * 64), 1, 0, a1, b0, VMC(6)); \
    PH(RDB(b1, sB1_0), STAGE(sB0_0, pB0, ((t) + 2) * 64), 1, 1, a1, b1, VMC(6)); \
    PH(NOP(),          STAGE(sA1_0, pA1, ((t) + 2) * 64), 0, 1, a0, b1, VMC(6)); \
  } while (0)

// odd tile t: cur = parity1 buffers, other = parity0
#define TILE_ODD(t) do {                                                       \
    PH({ RDA(a0, sA0_1); RDB(b0, sB0_1); },                                    \
       STAGE(sA0_0, pA0, ((t) + 1) * 64), 0, 0, a0, b0, VMC(6));               \
    PH(RDA(a1, sA1_1), STAGE(sB1_0, pB1, ((t) + 1) * 64), 1, 0, a1, b0, VMC(6)); \
    PH(RDB(b1, sB1_1), STAGE(sB0_1, pB0, ((t) + 2) * 64), 1, 1, a1, b1, VMC(6)); \
    PH(NOP(),          STAGE(sA1_1, pA1, ((t) + 2) * 64), 0, 1, a0, b1, VMC(6)); \
  } while (0)

// tile 62 (even): stage only A0(63),B1(63); tail drains 6/6/4/2
#define TILE_62() do {                                                         \
    PH({ RDA(a0, sA0_0); RDB(b0, sB0_0); },                                    \
       STAGE(sA0_1, pA0, 63 * 64), 0, 0, a0, b0, VMC(6));                      \
    PH(RDA(a1, sA1_0), STAGE(sB1_1, pB1, 63 * 64), 1, 0, a1, b0, VMC(6));      \
    PH(RDB(b1, sB1_0), NOP(), 1, 1, a1, b1, VMC(4));                           \
    PH(NOP(),          NOP(), 0, 1, a0, b1, VMC(2));                           \
  } while (0)

// tile 63 (odd): no stages; drain the rest at ph0
#define TILE_63() do {                                                         \
    PH({ RDA(a0, sA0_1); RDB(b0, sB0_1); }, NOP(), 0, 0, a0, b0, VMC(0));      \
    PH(RDA(a1, sA1_1), NOP(), 1, 0, a1, b0, NOP());                            \
    PH(RDB(b1, sB1_1), NOP(), 1, 1, a1, b1, NOP());                            \
    PH(NOP(),          NOP(), 0, 1, a0, b1, NOP());                            \
  } while (0)

  // prologue: mirrors steady-state issue order from t-2.ph2 onward:
  //   B0(0), A1(0), A0(0), B1(0), B0(1), A1(1); drain first 4 stages (vmcnt(4)),
  //   leave B0(1),A1(1) (4 loads) in flight.
  STAGE(sB0_0, pB0, 0);
  STAGE(sA1_0, pA1, 0);
  STAGE(sA0_0, pA0, 0);
  STAGE(sB1_0, pB1, 0);
  STAGE(sB0_1, pB0, 64);
  STAGE(sA1_1, pA1, 64);
  VMC(4);
  BAR();

#pragma unroll 1
  for (int t2 = 0; t2 < 62; t2 += 2) {
    TILE_EVEN(t2);
    TILE_ODD(t2 + 1);
  }
  TILE_62();
  TILE_63();

  // epilogue: D row=(lane>>4)*4+reg (M side), col=lane&15 (N side)
#pragma unroll
  for (int mq = 0; mq < 2; ++mq)
#pragma unroll
    for (int f = 0; f < 4; ++f) {
      float* po = out + (size_t)(bm * 256 + mq * 128 + wm * 64 + f * 16 + quad * 4) * NDIM;
#pragma unroll
      for (int nq = 0; nq < 2; ++nq)
#pragma unroll
        for (int g = 0; g < 2; ++g) {
          const int ocol = bn * 256 + nq * 128 + wn * 32 + g * 16 + r16;
          const float bb = bias[ocol];
          const f32x4 v = acc[mq][nq][f][g];
#pragma unroll
          for (int rg = 0; rg < 4; ++rg)
            po[(size_t)rg * NDIM + ocol] = v[rg] + bb;
        }
    }
}

extern "C" void kernel_launch(void* const* d_in, const int* in_sizes, int n_in,
                              void* d_out, int out_size, void* d_ws, size_t ws_size,
                              hipStream_t stream) {
  const float* x      = (const float*)d_in[0];  // [8192,4096]
  const float* W      = (const float*)d_in[1];  // [4096,4096]
  const float* bias   = (const float*)d_in[2];  // [4096]
  const float* lora_A = (const float*)d_in[3];  // [16,4096]
  const float* lora_B = (const float*)d_in[4];  // [4096,16]
  float* out = (float*)d_out;

  char* ws = (char*)d_ws;
  float* E = (float*)ws;                                     // 64 floats
  _Float16* Wh = (_Float16*)(ws + 1024);                     // 4096*4096*2 B
  _Float16* Xh = (_Float16*)(ws + 1024 + (size_t)NDIM * KDIM * 2);  // 8192*4096*2 B

  ns_kernel<<<dim3(4), dim3(256), 0, stream>>>(lora_A, lora_B, E);
  xcast_kernel<<<dim3((MDIM * KDIM) / (256 * 8)), dim3(256), 0, stream>>>(x, Xh);
  weff_kernel<<<dim3(512), dim3(256), 0, stream>>>(W, lora_A, lora_B, E, Wh);
  gemm_kernel<<<dim3(512), dim3(512), 0, stream>>>(Xh, Wh, bias, out);
}